// Round 16
// baseline (92.110 us; speedup 1.0000x reference)
//
#include <hip/hip_runtime.h>
#include <hip/hip_bf16.h>

// Problem constants (from reference)
#define BATCH   8
#define MROWS   2048      // C*P per batch
#define MTOT    16384     // BATCH*MROWS
#define DIM_Z   512
#define DIM_G   1024
#define EDIM    128
#define EPS     1e-6f
#define BK      64        // K-step

typedef unsigned short u16;
typedef unsigned int   u32;
typedef __attribute__((ext_vector_type(8))) short bf16x8;
typedef __attribute__((ext_vector_type(4))) float f32x4;
typedef __attribute__((ext_vector_type(4))) float fvec4;   // ext-vector for NT builtins
typedef __attribute__((ext_vector_type(4))) u32   u32x4;

// f32 -> bf16 round-to-nearest-even (bit trick; inputs are finite)
__device__ __forceinline__ u16 f2b(float f) {
    u32 x = __float_as_uint(f);
    u32 r = x + 0x7fffu + ((x >> 16) & 1u);
    return (u16)(r >> 16);
}

// async global->LDS, 16B per lane, dest = wave-uniform base + lane*16
#define GLD16(gsrc, ldst) __builtin_amdgcn_global_load_lds( \
    (const __attribute__((address_space(1))) unsigned int*)(gsrc), \
    (__attribute__((address_space(3))) unsigned int*)(ldst), 16, 0, 0)

// ---- kernel 1: u = a_emb @ Wu^T, v = a_emb @ Wv^T (coalesced); zero rsum ----
__global__ void uv_kernel(const float* __restrict__ emb, const int* __restrict__ idx,
                          const float* __restrict__ Wu, const float* __restrict__ Wv,
                          float* __restrict__ u, float* __restrict__ v,
                          float* __restrict__ rsum) {
    __shared__ float a[EDIM];
    int b = blockIdx.y;
    int t = threadIdx.x;
    if (blockIdx.x == 0)   // zero rsum slice for batch b (runs before GEMM1)
        for (int i = t; i < MROWS; i += 256) rsum[(size_t)b * MROWS + i] = 0.f;
    if (t < EDIM) a[t] = emb[(size_t)idx[b] * EDIM + t];
    __syncthreads();
    int tx = t & 31, ty = t >> 5;
    int oBase = blockIdx.x * 256;
    for (int o0 = 0; o0 < 256; o0 += 8) {
        int o = oBase + o0 + ty;
        const float* wrow = (o < DIM_G) ? (Wu + (size_t)o * EDIM)
                                        : (Wv + (size_t)(o - DIM_G) * EDIM);
        float s = 0.f;
#pragma unroll
        for (int q = 0; q < 4; ++q) s += a[q * 32 + tx] * wrow[q * 32 + tx];
        s += __shfl_xor(s, 1, 64);
        s += __shfl_xor(s, 2, 64);
        s += __shfl_xor(s, 4, 64);
        s += __shfl_xor(s, 8, 64);
        s += __shfl_xor(s, 16, 64);
        if (tx == 0) {
            if (o < DIM_G) u[b * DIM_G + o] = s;
            else           v[b * DIM_Z + (o - DIM_G)] = s;
        }
    }
}

// ---- kernel 2: cast qz f32 -> bf16, XCD-aligned (b = h&7): qzb lands dirty in
// the SAME XCD's L2 that gemm1's batch-b blocks (m-range decode) run on.
// NT loads (qz single-use from L3; don't pollute L2); NORMAL stores (qzb must
// be L2-hot — the r13 gemm2 lesson applied to gemm1's A side). ----
__global__ void cast_kernel(const float* __restrict__ in, u16* __restrict__ out) {
    int h = blockIdx.x;
    int b = h & 7, s = h >> 3;                    // s in [0,512) per batch
    size_t base = (size_t)b * MROWS * DIM_Z;      // elements
    int i = s * 256 + threadIdx.x;                // 8-elem chunk id within batch
    const fvec4* p = (const fvec4*)(in + base) + (size_t)i * 2;
    fvec4 f0 = __builtin_nontemporal_load(p);
    fvec4 f1 = __builtin_nontemporal_load(p + 1);
    union { u16 us[8]; u32x4 v; } o;
    o.us[0] = f2b(f0.x); o.us[1] = f2b(f0.y); o.us[2] = f2b(f0.z); o.us[3] = f2b(f0.w);
    o.us[4] = f2b(f1.x); o.us[5] = f2b(f1.y); o.us[6] = f2b(f1.z); o.us[7] = f2b(f1.w);
    ((u32x4*)(out + base))[i] = o.v;
}

// -- kernel 3: W[b,g,d] = W_base + u*v -> bf16 (+ transposed WT), b = h&7 --
// XCD-aligned so each batch's W/WT land dirty in the L2 of the XCD whose GEMM
// blocks (same b = xcd mapping) will read them.
__global__ void wpack_kernel(const float* __restrict__ Wbase,
                             const float* __restrict__ u, const float* __restrict__ v,
                             u16* __restrict__ W, u16* __restrict__ WT) {
    __shared__ u16 tile[32][33];
    int h = blockIdx.x;
    int b = h & 7, t8 = h >> 3;          // t8 in [0,512)
    int d0 = (t8 & 15) * 32, g0 = (t8 >> 4) * 32;
    int tx = threadIdx.x, ty = threadIdx.y;
    float vb = v[b * DIM_Z + d0 + tx];
#pragma unroll
    for (int j = 0; j < 4; ++j) {
        int g = g0 + ty + j * 8;
        u16 h16 = f2b(Wbase[(size_t)g * DIM_Z + d0 + tx] + u[b * DIM_G + g] * vb);
        W[((size_t)b * DIM_G + g) * DIM_Z + d0 + tx] = h16;
        tile[ty + j * 8][tx] = h16;
    }
    __syncthreads();
#pragma unroll
    for (int j = 0; j < 4; ++j)
        WT[((size_t)b * DIM_Z + d0 + ty + j * 8) * DIM_G + g0 + tx] =
            tile[tx][ty + j * 8];
}

// ------- GEMM (the r13-proven 24 µs structure, both GEMMs now identical) -------
// C[m,n] = sum_k A[m,k] * Bt[n,k]. Both operands bf16 via global_load_lds
// (linear LDS dest, source chunk pre-swizzled cw = c'^(row&7); reads apply the
// same XOR — rule #21, 0 conflicts measured). 128x128 tile, 4 waves, BK=64,
// (256,4), simple 2-barrier loop (5 pipeline variants proven neutral).
// XCD decode: xcd = h&7 owns a contiguous batch-pure m-range; n-fastest within
// (the 2^NTLOG n-tiles sharing an A-panel are consecutive -> L2-hit reuse).
// EPI=0: relu -> bf16 NORMAL store (qg L2-hot for GEMM2) + rsum atomics.
// EPI=1: scale by 1/max(rsum[m],eps) -> f32 NT store (out never re-read).
template <int EPI, int NTLOG>
__global__ __launch_bounds__(256, 4)
void gemm_bt(const u16* __restrict__ Aall, const u16* __restrict__ Btall,
             void* __restrict__ Call, float* __restrict__ rsum,
             int N, int K) {
    __shared__ u16 As[128 * BK];   // 16 KB
    __shared__ u16 Bs[128 * BK];   // 16 KB

    int h = blockIdx.x;
    int xcd = h & 7, idx = h >> 3;
    int tile = xcd * (16 << NTLOG) + idx;     // 16 mT x 2^NTLOG nT per XCD
    int mBase = (tile >> NTLOG) * 128;
    int nBase = (tile & ((1 << NTLOG) - 1)) * 128;
    int b = mBase >> 11;                       // == xcd (batch-pure m-range)

    int tid  = threadIdx.x;
    int lane = tid & 63, wid = tid >> 6;
    int wm = wid >> 1, wn = wid & 1;
    int lr = lane & 15, lg = lane >> 4;

    f32x4 acc[4][4] = {};

    int sRow = tid >> 3;                       // 0..31
    int cw   = (tid & 7) ^ (sRow & 7);
    const u16* aSrc = Aall + (size_t)(mBase + sRow) * K + cw * 8;
    const u16* bSrc = Btall + (size_t)b * (size_t)N * K
                            + (size_t)(nBase + sRow) * K + cw * 8;

    for (int kt = 0; kt < K; kt += BK) {
        __syncthreads();   // previous tile's reads done before overwrite
#pragma unroll
        for (int r = 0; r < 4; ++r) {
            GLD16(aSrc + (size_t)r * 32 * K + kt, &As[(r * 256 + wid * 64) * 8]);
            GLD16(bSrc + (size_t)r * 32 * K + kt, &Bs[(r * 256 + wid * 64) * 8]);
        }
        __syncthreads();   // tile landed
#pragma unroll
        for (int ks = 0; ks < 2; ++ks) {
            bf16x8 af[4], bfr[4];
#pragma unroll
            for (int mi = 0; mi < 4; ++mi) {
                int row = wm * 64 + mi * 16 + lr;
                int cq  = (ks * 4 + lg) ^ (row & 7);
                af[mi] = *(const bf16x8*)&As[row * BK + cq * 8];
            }
#pragma unroll
            for (int ni = 0; ni < 4; ++ni) {
                int row = wn * 64 + ni * 16 + lr;
                int cq  = (ks * 4 + lg) ^ (row & 7);
                bfr[ni] = *(const bf16x8*)&Bs[row * BK + cq * 8];
            }
            __builtin_amdgcn_s_setprio(1);
#pragma unroll
            for (int mi = 0; mi < 4; ++mi)
#pragma unroll
                for (int ni = 0; ni < 4; ++ni)
                    acc[mi][ni] = __builtin_amdgcn_mfma_f32_16x16x32_bf16(
                        af[mi], bfr[ni], acc[mi][ni], 0, 0, 0);
            __builtin_amdgcn_s_setprio(0);
        }
    }

    int mw = mBase + wm * 64, nw = nBase + wn * 64;
    if (EPI == 0) {
        u16* C = (u16*)Call;
#pragma unroll
        for (int mi = 0; mi < 4; ++mi)
#pragma unroll
            for (int r = 0; r < 4; ++r) {
                int m = mw + mi * 16 + lg * 4 + r;
                float vals[4];
                float s = 0.f;
#pragma unroll
                for (int ni = 0; ni < 4; ++ni) {
                    vals[ni] = fmaxf(acc[mi][ni][r], 0.f);
                    s += vals[ni];
                }
#pragma unroll
                for (int ni = 0; ni < 4; ++ni)
                    C[(size_t)m * N + nw + ni * 16 + lr] = f2b(vals[ni]);
                s += __shfl_xor(s, 1, 64);
                s += __shfl_xor(s, 2, 64);
                s += __shfl_xor(s, 4, 64);
                s += __shfl_xor(s, 8, 64);
                if (lr == 0) atomicAdd(&rsum[m], s);
            }
    } else {
        float* C = (float*)Call;
#pragma unroll
        for (int mi = 0; mi < 4; ++mi)
#pragma unroll
            for (int r = 0; r < 4; ++r) {
                int m = mw + mi * 16 + lg * 4 + r;
                float inv = 1.f / fmaxf(rsum[m], EPS);
#pragma unroll
                for (int ni = 0; ni < 4; ++ni)
                    __builtin_nontemporal_store(acc[mi][ni][r] * inv,
                        &C[(size_t)m * N + nw + ni * 16 + lr]);
            }
    }
}

extern "C" void kernel_launch(void* const* d_in, const int* in_sizes, int n_in,
                              void* d_out, int out_size, void* d_ws, size_t ws_size,
                              hipStream_t stream) {
    const float* qz    = (const float*)d_in[0];
    const int*   attr  = (const int*)d_in[1];
    const float* Wbase = (const float*)d_in[2];
    const float* emb   = (const float*)d_in[3];
    const float* Wu    = (const float*)d_in[4];
    const float* Wv    = (const float*)d_in[5];
    float* out = (float*)d_out;

    // workspace carve-up (all 256B aligned)
    char* ws = (char*)d_ws;
    size_t off = 0;
    auto alloc = [&](size_t bytes) -> void* {
        void* p = ws + off;
        off = (off + bytes + 255) & ~(size_t)255;
        return p;
    };
    float* u    = (float*)alloc((size_t)BATCH * DIM_G * 4);
    float* v    = (float*)alloc((size_t)BATCH * DIM_Z * 4);
    float* rsum = (float*)alloc((size_t)MTOT * 4);
    u16*   qzb  = (u16*)  alloc((size_t)MTOT * DIM_Z * 2);
    u16*   W    = (u16*)  alloc((size_t)BATCH * DIM_G * DIM_Z * 2);
    u16*   WT   = (u16*)  alloc((size_t)BATCH * DIM_G * DIM_Z * 2);
    u16*   qg   = (u16*)  alloc((size_t)MTOT * DIM_G * 2);
    if (off > ws_size) return;  // fail loudly (zero output) rather than corrupt

    uv_kernel<<<dim3(6, BATCH), dim3(256), 0, stream>>>(emb, attr, Wu, Wv, u, v, rsum);

    // cast qz -> bf16, XCD-aligned: qzb L2-hot where gemm1 will read it
    cast_kernel<<<dim3(4096), dim3(256), 0, stream>>>(qz, qzb);

    wpack_kernel<<<dim3(4096), dim3(32, 8), 0, stream>>>(Wbase, u, v, W, WT);

    // GEMM1: qg = relu(qzb @ W[b]^T) + rsum epilogue.
    // 16 mT x 8 nT x 8 xcd = 1024 blocks (NTLOG=3)
    gemm_bt<0, 3><<<dim3(1024), dim3(256), 0, stream>>>(
        qzb, W, qg, rsum, DIM_G, DIM_Z);

    // GEMM2: out = (qg @ WT[b]^T) / max(rsum,eps).
    // 16 mT x 4 nT x 8 xcd = 512 blocks (NTLOG=2)
    gemm_bt<1, 2><<<dim3(512), dim3(256), 0, stream>>>(
        qg, WT, out, rsum, DIM_Z, DIM_G);
}

// Round 17
// 81.191 us; speedup vs baseline: 1.1345x; 1.1345x over previous
//
#include <hip/hip_runtime.h>
#include <hip/hip_bf16.h>

// Problem constants (from reference)
#define BATCH   8
#define MROWS   2048      // C*P per batch
#define MTOT    16384     // BATCH*MROWS
#define DIM_Z   512
#define DIM_G   1024
#define EDIM    128
#define EPS     1e-6f
#define BK      64        // K-step

typedef unsigned short u16;
typedef unsigned int   u32;
typedef __attribute__((ext_vector_type(8))) short bf16x8;
typedef __attribute__((ext_vector_type(4))) float f32x4;

// f32 -> bf16 round-to-nearest-even (bit trick; inputs are finite)
__device__ __forceinline__ u16 f2b(float f) {
    u32 x = __float_as_uint(f);
    u32 r = x + 0x7fffu + ((x >> 16) & 1u);
    return (u16)(r >> 16);
}

// packed f32 pair -> 2x bf16 in one u32 (RNE), single VALU inst on gfx950
__device__ __forceinline__ u32 cvtpk(float lo, float hi) {
    u32 r;
    asm("v_cvt_pk_bf16_f32 %0, %1, %2" : "=v"(r) : "v"(lo), "v"(hi));
    return r;
}

// async global->LDS, 16B per lane, dest = wave-uniform base + lane*16
#define GLD16(gsrc, ldst) __builtin_amdgcn_global_load_lds( \
    (const __attribute__((address_space(1))) unsigned int*)(gsrc), \
    (__attribute__((address_space(3))) unsigned int*)(ldst), 16, 0, 0)

// ---- kernel 1: u = a_emb @ Wu^T, v = a_emb @ Wv^T (coalesced); zero rsum ----
__global__ void uv_kernel(const float* __restrict__ emb, const int* __restrict__ idx,
                          const float* __restrict__ Wu, const float* __restrict__ Wv,
                          float* __restrict__ u, float* __restrict__ v,
                          float* __restrict__ rsum) {
    __shared__ float a[EDIM];
    int b = blockIdx.y;
    int t = threadIdx.x;
    if (blockIdx.x == 0)   // zero rsum slice for batch b (runs before GEMM1)
        for (int i = t; i < MROWS; i += 256) rsum[(size_t)b * MROWS + i] = 0.f;
    if (t < EDIM) a[t] = emb[(size_t)idx[b] * EDIM + t];
    __syncthreads();
    int tx = t & 31, ty = t >> 5;
    int oBase = blockIdx.x * 256;
    for (int o0 = 0; o0 < 256; o0 += 8) {
        int o = oBase + o0 + ty;
        const float* wrow = (o < DIM_G) ? (Wu + (size_t)o * EDIM)
                                        : (Wv + (size_t)(o - DIM_G) * EDIM);
        float s = 0.f;
#pragma unroll
        for (int q = 0; q < 4; ++q) s += a[q * 32 + tx] * wrow[q * 32 + tx];
        s += __shfl_xor(s, 1, 64);
        s += __shfl_xor(s, 2, 64);
        s += __shfl_xor(s, 4, 64);
        s += __shfl_xor(s, 8, 64);
        s += __shfl_xor(s, 16, 64);
        if (tx == 0) {
            if (o < DIM_G) u[b * DIM_G + o] = s;
            else           v[b * DIM_Z + (o - DIM_G)] = s;
        }
    }
}

// -- kernel 2: W[b,g,d] = W_base + u*v -> bf16 (+ transposed WT), b = h&7 --
// XCD-aligned so each batch's W/WT land dirty in the L2 of the XCD whose GEMM
// blocks (same b = xcd mapping) will read them.
__global__ void wpack_kernel(const float* __restrict__ Wbase,
                             const float* __restrict__ u, const float* __restrict__ v,
                             u16* __restrict__ W, u16* __restrict__ WT) {
    __shared__ u16 tile[32][33];
    int h = blockIdx.x;
    int b = h & 7, t8 = h >> 3;          // t8 in [0,512)
    int d0 = (t8 & 15) * 32, g0 = (t8 >> 4) * 32;
    int tx = threadIdx.x, ty = threadIdx.y;
    float vb = v[b * DIM_Z + d0 + tx];
#pragma unroll
    for (int j = 0; j < 4; ++j) {
        int g = g0 + ty + j * 8;
        u16 h16 = f2b(Wbase[(size_t)g * DIM_Z + d0 + tx] + u[b * DIM_G + g] * vb);
        W[((size_t)b * DIM_G + g) * DIM_Z + d0 + tx] = h16;
        tile[ty + j * 8][tx] = h16;
    }
    __syncthreads();
#pragma unroll
    for (int j = 0; j < 4; ++j)
        WT[((size_t)b * DIM_Z + d0 + ty + j * 8) * DIM_G + g0 + tx] =
            tile[tx][ty + j * 8];
}

// ---------- GEMM1 (FAT TILE): qg = relu(qz @ W[b]^T); rsum[m] = row-sum ----------
// 128m x 256n tile, 4 waves of 64x128 (acc 4x8) -> block-iterations HALVE
// (4096 vs 8192) and FLOP per staged LDS byte rises 1.37x (r12 evidence: the
// only round where GEMM time visibly dropped). A = qz f32 fused (issue-early
// f32 loads, v_cvt_pk_bf16_f32, swizzled ds_write — r15-proven). B = W[b] via
// global_load_lds (source chunk pre-swizzled cw = c'^(row&7); reads same XOR).
// LDS 48 KB, LB(256,2). XCD decode: xcd = h&7 owns batch xcd's m-range.
// qg stored NORMAL (L2-hot for GEMM2 — r13 lesson).
__global__ __launch_bounds__(256, 2)
void gemm1(const float* __restrict__ qz, const u16* __restrict__ Wall,
           u16* __restrict__ qg, float* __restrict__ rsum) {
    const int N = DIM_G, K = DIM_Z;
    __shared__ u16 As[128 * BK];   // 16 KB
    __shared__ u16 Bs[256 * BK];   // 32 KB

    int h = blockIdx.x;
    int xcd = h & 7, idx = h >> 3;
    int tile = xcd * 64 + idx;               // 16 mT x 4 nT per XCD
    int mBase = (tile >> 2) * 128;
    int nBase = (tile & 3) * 256;
    int b = mBase >> 11;                      // == xcd

    int tid  = threadIdx.x;
    int lane = tid & 63, wid = tid >> 6;
    int wm = wid >> 1, wn = wid & 1;          // 2M x 2N fat waves
    int lr = lane & 15, lg = lane >> 4;

    f32x4 acc[4][8] = {};

    int sRow = tid >> 3;                      // 0..31
    int sC   = tid & 7;
    int cw   = sC ^ (sRow & 7);
    const float* aSrc = qz + (size_t)(mBase + sRow) * K + sC * 8;     // straight
    const u16*   bSrc = Wall + (size_t)b * DIM_G * DIM_Z
                             + (size_t)(nBase + sRow) * K + cw * 8;   // pre-swz

    for (int kt = 0; kt < K; kt += BK) {
        float4 alo[4], ahi[4];
#pragma unroll
        for (int r = 0; r < 4; ++r) {         // issue-early: no LDS hazard
            const float* g = aSrc + (size_t)r * 32 * K + kt;
            alo[r] = *(const float4*)g;
            ahi[r] = *(const float4*)(g + 4);
        }
        __syncthreads();   // previous tile's reads done before overwrite
#pragma unroll
        for (int r = 0; r < 8; ++r)           // B: 256 rows
            GLD16(bSrc + (size_t)r * 32 * K + kt, &Bs[(r * 256 + wid * 64) * 8]);
#pragma unroll
        for (int r = 0; r < 4; ++r) {         // packed cvt + swizzled ds_write
            uint4 q;
            q.x = cvtpk(alo[r].x, alo[r].y);
            q.y = cvtpk(alo[r].z, alo[r].w);
            q.z = cvtpk(ahi[r].x, ahi[r].y);
            q.w = cvtpk(ahi[r].z, ahi[r].w);
            *(uint4*)&As[(r * 32 + sRow) * BK + cw * 8] = q;
        }
        __syncthreads();   // tile landed
#pragma unroll
        for (int ks = 0; ks < 2; ++ks) {
            bf16x8 af[4], bfr[8];
#pragma unroll
            for (int mi = 0; mi < 4; ++mi) {
                int row = wm * 64 + mi * 16 + lr;
                int cq  = (ks * 4 + lg) ^ (row & 7);
                af[mi] = *(const bf16x8*)&As[row * BK + cq * 8];
            }
#pragma unroll
            for (int ni = 0; ni < 8; ++ni) {
                int row = wn * 128 + ni * 16 + lr;
                int cq  = (ks * 4 + lg) ^ (row & 7);
                bfr[ni] = *(const bf16x8*)&Bs[row * BK + cq * 8];
            }
            __builtin_amdgcn_s_setprio(1);
#pragma unroll
            for (int mi = 0; mi < 4; ++mi)
#pragma unroll
                for (int ni = 0; ni < 8; ++ni)
                    acc[mi][ni] = __builtin_amdgcn_mfma_f32_16x16x32_bf16(
                        af[mi], bfr[ni], acc[mi][ni], 0, 0, 0);
            __builtin_amdgcn_s_setprio(0);
        }
    }

    int mw = mBase + wm * 64, nw = nBase + wn * 128;
#pragma unroll
    for (int mi = 0; mi < 4; ++mi)
#pragma unroll
        for (int r = 0; r < 4; ++r) {
            int m = mw + mi * 16 + lg * 4 + r;
            float vals[8];
            float s = 0.f;
#pragma unroll
            for (int ni = 0; ni < 8; ++ni) {
                vals[ni] = fmaxf(acc[mi][ni][r], 0.f);
                s += vals[ni];
            }
#pragma unroll
            for (int ni = 0; ni < 8; ++ni)
                qg[(size_t)m * N + nw + ni * 16 + lr] = f2b(vals[ni]);
            s += __shfl_xor(s, 1, 64);
            s += __shfl_xor(s, 2, 64);
            s += __shfl_xor(s, 4, 64);
            s += __shfl_xor(s, 8, 64);
            if (lr == 0) atomicAdd(&rsum[m], s);
        }
}

// ---------------- GEMM2: out = (qg @ WT[b]^T) / max(rsum,eps) ----------------
// The champion ~24 µs structure (UNCHANGED): both operands via global_load_lds,
// 128x128, (256,4), per-XCD m-range matching GEMM1 (qg L2-hot), NT out store.
__global__ __launch_bounds__(256, 4)
void gemm2(const u16* __restrict__ qg, const u16* __restrict__ WTall,
           const float* __restrict__ rsum, float* __restrict__ out) {
    const int N = DIM_Z, K = DIM_G;
    __shared__ u16 As[128 * BK];   // 16 KB
    __shared__ u16 Bs[128 * BK];   // 16 KB

    int h = blockIdx.x;
    int xcd = h & 7, idx = h >> 3;
    int tile = xcd * 64 + idx;               // 16 mT x 4 nT per XCD
    int mBase = (tile >> 2) * 128;
    int nBase = (tile & 3) * 128;
    int b = mBase >> 11;                      // == xcd

    int tid  = threadIdx.x;
    int lane = tid & 63, wid = tid >> 6;
    int wm = wid >> 1, wn = wid & 1;
    int lr = lane & 15, lg = lane >> 4;

    f32x4 acc[4][4] = {};

    int sRow = tid >> 3;
    int cw   = (tid & 7) ^ (sRow & 7);
    const u16* aSrc = qg + (size_t)(mBase + sRow) * K + cw * 8;
    const u16* bSrc = WTall + (size_t)b * DIM_Z * DIM_G
                            + (size_t)(nBase + sRow) * K + cw * 8;

    for (int kt = 0; kt < K; kt += BK) {
        __syncthreads();
#pragma unroll
        for (int r = 0; r < 4; ++r) {
            GLD16(aSrc + (size_t)r * 32 * K + kt, &As[(r * 256 + wid * 64) * 8]);
            GLD16(bSrc + (size_t)r * 32 * K + kt, &Bs[(r * 256 + wid * 64) * 8]);
        }
        __syncthreads();
#pragma unroll
        for (int ks = 0; ks < 2; ++ks) {
            bf16x8 af[4], bfr[4];
#pragma unroll
            for (int mi = 0; mi < 4; ++mi) {
                int row = wm * 64 + mi * 16 + lr;
                int cq  = (ks * 4 + lg) ^ (row & 7);
                af[mi] = *(const bf16x8*)&As[row * BK + cq * 8];
            }
#pragma unroll
            for (int ni = 0; ni < 4; ++ni) {
                int row = wn * 64 + ni * 16 + lr;
                int cq  = (ks * 4 + lg) ^ (row & 7);
                bfr[ni] = *(const bf16x8*)&Bs[row * BK + cq * 8];
            }
            __builtin_amdgcn_s_setprio(1);
#pragma unroll
            for (int mi = 0; mi < 4; ++mi)
#pragma unroll
                for (int ni = 0; ni < 4; ++ni)
                    acc[mi][ni] = __builtin_amdgcn_mfma_f32_16x16x32_bf16(
                        af[mi], bfr[ni], acc[mi][ni], 0, 0, 0);
            __builtin_amdgcn_s_setprio(0);
        }
    }

    int mw = mBase + wm * 64, nw = nBase + wn * 64;
#pragma unroll
    for (int mi = 0; mi < 4; ++mi)
#pragma unroll
        for (int r = 0; r < 4; ++r) {
            int m = mw + mi * 16 + lg * 4 + r;
            float inv = 1.f / fmaxf(rsum[m], EPS);
#pragma unroll
            for (int ni = 0; ni < 4; ++ni)
                __builtin_nontemporal_store(acc[mi][ni][r] * inv,
                    &out[(size_t)m * N + nw + ni * 16 + lr]);
        }
}

extern "C" void kernel_launch(void* const* d_in, const int* in_sizes, int n_in,
                              void* d_out, int out_size, void* d_ws, size_t ws_size,
                              hipStream_t stream) {
    const float* qz    = (const float*)d_in[0];
    const int*   attr  = (const int*)d_in[1];
    const float* Wbase = (const float*)d_in[2];
    const float* emb   = (const float*)d_in[3];
    const float* Wu    = (const float*)d_in[4];
    const float* Wv    = (const float*)d_in[5];
    float* out = (float*)d_out;

    // workspace carve-up (all 256B aligned)
    char* ws = (char*)d_ws;
    size_t off = 0;
    auto alloc = [&](size_t bytes) -> void* {
        void* p = ws + off;
        off = (off + bytes + 255) & ~(size_t)255;
        return p;
    };
    float* u    = (float*)alloc((size_t)BATCH * DIM_G * 4);
    float* v    = (float*)alloc((size_t)BATCH * DIM_Z * 4);
    float* rsum = (float*)alloc((size_t)MTOT * 4);
    u16*   W    = (u16*)  alloc((size_t)BATCH * DIM_G * DIM_Z * 2);
    u16*   WT   = (u16*)  alloc((size_t)BATCH * DIM_G * DIM_Z * 2);
    u16*   qg   = (u16*)  alloc((size_t)MTOT * DIM_G * 2);
    if (off > ws_size) return;  // fail loudly (zero output) rather than corrupt

    uv_kernel<<<dim3(6, BATCH), dim3(256), 0, stream>>>(emb, attr, Wu, Wv, u, v, rsum);

    wpack_kernel<<<dim3(4096), dim3(32, 8), 0, stream>>>(Wbase, u, v, W, WT);

    // GEMM1 (fat 128x256): 16 mT x 4 nT x 8 xcd = 512 blocks
    gemm1<<<dim3(512), dim3(256), 0, stream>>>(qz, W, qg, rsum);

    // GEMM2 (champion 128x128): 16 mT x 4 nT x 8 xcd = 512 blocks
    gemm2<<<dim3(512), dim3(256), 0, stream>>>(qg, WT, rsum, out);
}